// Round 1
// 149.625 us; speedup vs baseline: 1.0340x; 1.0340x over previous
//
#include <hip/hip_runtime.h>

// Problem shape (fixed by reference):
//   feat_s, feat_t : [64, 256, 32, 32] float32, integer values in [0,256)
//   out            : scalar float32
#define NBATCH    64
#define BINS      256
#define PER_BATCH (256 * 32 * 32)   // 262144 elements per batch
#define THREADS   256
#define CHUNKS    16                // blocks per batch-tensor
#define F4_PER_CHUNK (PER_BATCH / 4 / CHUNKS)   // 4096 float4 per block
#define F4_PER_THREAD (F4_PER_CHUNK / THREADS)  // 16 float4 = 64 elems/thread

// ---------------------------------------------------------------------------
// Kernel 1: per-batch histograms.
// LDS: 256 rows (one per bin) x 16 columns of u32 counters = 16 KiB.
//   col = tid & 15  -> 16 threads/column, counter max 16*64 = 1024 (no
//   overflow proof needed). Word = bin*16 + col; bank = (16*(bin&1)+col)%32:
//   average 2 lanes/bank (free, m136), worst-case 4-way on parity collision
//   (1.58x on a pipe that is <10% of time). Same-word collision prob 1/256
//   per lane pair -> negligible atomic serialization.
// PROC is 3 VALU + 1 ds_add (increment is inline constant 1) vs ~6 VALU in
// the packed-byte scheme.
// 16 KiB x 8 blocks = 128 KiB LDS -> 8 blocks/CU = 32 waves/CU (wave cap).
// grid = 2048 blocks = 256 CU x 8 = EXACTLY one resident generation: no
// second-generation tail (the prior 32 KiB layout ran 1280 + 768 stragglers).
// __launch_bounds__(256,8) holds VGPR <= 64 (prior kernel was 44 with the
// same 8-deep prefetch, new inner loop is simpler).
// Each block writes its own 256-bin u16 slab (max count/bin = 16384 < 2^16).
// Block 0 also zeroes the completion flag used by kernel 2 (stream-ordered
// before kernel 2 starts, and re-zeroed every iteration => re-poison safe).
// ---------------------------------------------------------------------------
__global__ __launch_bounds__(THREADS, 8) void hist_kernel(
    const float* __restrict__ fs, const float* __restrict__ ft,
    unsigned short* __restrict__ phist, unsigned* __restrict__ flag) {
  __shared__ unsigned sh[BINS * 16];  // 16 KiB
  const int tid = threadIdx.x;
  if (blockIdx.x == 0 && tid == 0) *flag = 0u;

  // zero LDS: 4096 words / 256 thr = 16 words = 4 x uint4 per thread
  uint4* shv = (uint4*)sh;
#pragma unroll
  for (int k = 0; k < 4; ++k) shv[k * THREADS + tid] = make_uint4(0, 0, 0, 0);
  __syncthreads();

  const int tb    = blockIdx.x >> 4;   // 0..127 : batch-tensor index
  const int chunk = blockIdx.x & 15;
  const float* src   = (tb < NBATCH) ? fs : ft;
  const int    batch = tb & (NBATCH - 1);
  const float4* p = (const float4*)(src + (size_t)batch * PER_BATCH)
                    + (size_t)chunk * F4_PER_CHUNK;

  const unsigned colb = ((unsigned)tid & 15u) << 2;  // column byte offset

#define PROC1(x) {                                              \
    unsigned b = (unsigned)(x);                                 \
    atomicAdd((unsigned*)((char*)sh + ((b << 6) + colb)), 1u); }
#define PROC4(v) { PROC1(v.x) PROC1(v.y) PROC1(v.z) PROC1(v.w) }

  // 8-deep float4 prefetch pipeline over 16 float4 per thread
  float4 c[8];
#pragma unroll
  for (int k = 0; k < 8; ++k) c[k] = p[k * THREADS + tid];
#pragma unroll
  for (int k = 0; k < 8; ++k) {
    float4 n = p[(8 + k) * THREADS + tid];
    PROC4(c[k])
    c[k] = n;
  }
#pragma unroll
  for (int k = 0; k < 8; ++k) PROC4(c[k])
  __syncthreads();

  // Flush: thread t owns bin t: sum its 16-column row. Rotation (c+t)&15
  // keeps 2 lanes/bank (bank = 16*(t&1) + col). Max sum 16384 -> u16 slab.
  unsigned cnt = 0;
#pragma unroll
  for (int c = 0; c < 16; ++c)
    cnt += sh[((unsigned)tid << 4) + (((unsigned)c + (unsigned)tid) & 15u)];
  phist[blockIdx.x * BINS + tid] = (unsigned short)cnt;
}

// ---------------------------------------------------------------------------
// Kernel 2: per-batch KL partial, one block per batch (64 blocks x 256 thr).
// Sums the 16 u16 chunk-histograms per tensor inline (coalesced), then fp64
// softmax/KL (result is a ~1e-3 sum of cancelling terms; threshold 1.9e-5).
// finalize is FUSED: each block release-stores its partial and bumps a
// device-scope counter; the last block (agent-scope acquire) reduces the 64
// partials in-wave and writes the scalar output. One fewer launch.
// ---------------------------------------------------------------------------
__global__ __launch_bounds__(256) void kl_batch(
    const unsigned short* __restrict__ phist, double* __restrict__ partial,
    unsigned* __restrict__ flag, float* __restrict__ out) {
  __shared__ double reda[4], redb[4];
  __shared__ int amLast;
  const int n = blockIdx.x, tid = threadIdx.x;
  const int w = tid >> 6, lane = tid & 63;

  int hs = 0, ht = 0;
#pragma unroll
  for (int c = 0; c < CHUNKS; ++c) {
    hs += (int)phist[(n * CHUNKS + c) * BINS + tid];
    ht += (int)phist[((NBATCH + n) * CHUNKS + c) * BINS + tid];
  }

  // logits = log(hist + 1e-8) / T, T = 4
  double ls = log((double)hs + 1e-8) * 0.25;
  double lt = log((double)ht + 1e-8) * 0.25;

  double ms = ls, mt = lt;
  for (int off = 32; off; off >>= 1) {
    ms = fmax(ms, __shfl_xor(ms, off));
    mt = fmax(mt, __shfl_xor(mt, off));
  }
  if (lane == 0) { reda[w] = ms; redb[w] = mt; }
  __syncthreads();
  ms = fmax(fmax(reda[0], reda[1]), fmax(reda[2], reda[3]));
  mt = fmax(fmax(redb[0], redb[1]), fmax(redb[2], redb[3]));
  __syncthreads();

  double ss = exp(ls - ms), st = exp(lt - mt);
  for (int off = 32; off; off >>= 1) {
    ss += __shfl_xor(ss, off);
    st += __shfl_xor(st, off);
  }
  if (lane == 0) { reda[w] = ss; redb[w] = st; }
  __syncthreads();
  ss = reda[0] + reda[1] + reda[2] + reda[3];
  st = redb[0] + redb[1] + redb[2] + redb[3];
  const double lse_s = ms + log(ss);
  const double lse_t = mt + log(st);

  const double lpt = lt - lse_t;
  const double lps = ls - lse_s;
  double term = exp(lpt) * (lpt - lps);
  for (int off = 32; off; off >>= 1) term += __shfl_xor(term, off);
  __syncthreads();                 // protect reda reuse
  if (lane == 0) reda[w] = term;
  __syncthreads();

  if (tid == 0) {
    double bsum = reda[0] + reda[1] + reda[2] + reda[3];
    __hip_atomic_store(&partial[n], bsum, __ATOMIC_RELEASE,
                       __HIP_MEMORY_SCOPE_AGENT);
    unsigned prev = __hip_atomic_fetch_add(flag, 1u, __ATOMIC_ACQ_REL,
                                           __HIP_MEMORY_SCOPE_AGENT);
    amLast = (prev == (unsigned)(NBATCH - 1)) ? 1 : 0;
  }
  __syncthreads();

  if (amLast && tid < 64) {
    double v = __hip_atomic_load(&partial[tid], __ATOMIC_ACQUIRE,
                                 __HIP_MEMORY_SCOPE_AGENT);
    for (int off = 32; off; off >>= 1) v += __shfl_xor(v, off);
    if (tid == 0) out[0] = (float)(v * 0.25);   // * T^2 / N = 16/64
  }
}

// ---------------------------------------------------------------------------
extern "C" void kernel_launch(void* const* d_in, const int* in_sizes, int n_in,
                              void* d_out, int out_size, void* d_ws, size_t ws_size,
                              hipStream_t stream) {
  const float* fs = (const float*)d_in[0];
  const float* ft = (const float*)d_in[1];
  // ws: 2048 block-private 256-bin u16 slabs (1 MiB) + 64 doubles + flag.
  unsigned short* phist = (unsigned short*)d_ws;
  double* partial = (double*)((char*)d_ws +
                              (size_t)128 * CHUNKS * BINS * sizeof(unsigned short));
  unsigned* flag = (unsigned*)((char*)partial + NBATCH * sizeof(double));

  hist_kernel<<<dim3(128 * CHUNKS), dim3(THREADS), 0, stream>>>(fs, ft, phist, flag);
  kl_batch<<<dim3(NBATCH), dim3(256), 0, stream>>>(phist, partial, flag, (float*)d_out);
}